// Round 10
// baseline (127.503 us; speedup 1.0000x reference)
//
#include <hip/hip_runtime.h>
#include <math.h>

// Problem constants
#define DD     2048
#define EE     64
#define NTOK   8192
#define BM     64               // tokens per m-tile
#define KSPLIT 4                // K-split across blockIdx.y
#define KQ     512              // k per block
#define BK     64               // k per staged chunk (doubled vs R9)
#define NCH    (KQ / BK)        // 8 chunks

// Output layout (all read back as float32 by harness)
#define PROB_OFF 0
#define IDX_OFF  524288
#define MASK_OFF 540672
#define MASK_K_STRIDE (NTOK * EE)

// LDS: 2-deep pipeline. xbuf[2] @ 0/16K (16 KB), bbuf[2] @ 32K/64K (32 KB)
#define XBUF_OFF(b) ((b) * 16384)
#define BBUF_OFF(b) (32768 + (b) * 32768)
#define LDS_BYTES   98304        // 96 KB -> 1 block/CU

typedef __bf16 bf16x8 __attribute__((ext_vector_type(8)));
typedef float  f32x16 __attribute__((ext_vector_type(16)));

__device__ __forceinline__ unsigned f2bf_rne(float f) {
  unsigned u = __float_as_uint(f);
  return (u + 0x7fffu + ((u >> 16) & 1u)) >> 16;   // low 16 bits = bf16
}
__device__ __forceinline__ float bf2f(unsigned h) {
  return __uint_as_float(h << 16);
}

// async 16B global->LDS DMA (no VGPR round-trip; tracked by vmcnt)
__device__ __forceinline__ void gl_lds16(const void* g, void* l) {
  __builtin_amdgcn_global_load_lds(
      (const __attribute__((address_space(1))) unsigned int*)g,
      (__attribute__((address_space(3))) unsigned int*)l,
      16, 0, 0);
}

// ---------------------------------------------------------------------------
// prep_w: weights -> MFMA-fragment-ready bf16 hi/lo in workspace (1 MB).
// Fragment bijection (validated end-to-end by R1-R9 passes):
//   slot (g, nt, mat, lane, i)  <->  B[k][c],  k = 16*g + 8*(lane>>5) + i,
//   c = 32*nt + (lane&31),  (c<64 -> gate, else noise).
// Byte addr = ((g*4 + nt)*2 + mat)*1024 + lane*16 + 2*i.
// ---------------------------------------------------------------------------
__global__ __launch_bounds__(256) void prep_w(
    const float* __restrict__ wg, const float* __restrict__ wn,
    unsigned char* __restrict__ wsb)
{
  const int t  = blockIdx.x * 256 + threadIdx.x;   // 0..32767
  const int l  = t & 63;
  const int nt = (t >> 6) & 3;
  const int g  = t >> 8;                           // 0..127 (16-k steps)
  const int colg = nt * 32 + (l & 31);             // 0..127
  const int kb   = g * 16 + 8 * (l >> 5);
  const float* wsrc = (colg < EE) ? (wg + colg) : (wn + (colg - EE));

  unsigned hv[8], lv[8];
#pragma unroll
  for (int i = 0; i < 8; ++i) {
    const float v = wsrc[(size_t)(kb + i) * EE];
    const unsigned h = f2bf_rne(v);
    hv[i] = h;
    lv[i] = f2bf_rne(v - bf2f(h));
  }
  uint4 hq, lq;
  hq.x = hv[0] | (hv[1] << 16); hq.y = hv[2] | (hv[3] << 16);
  hq.z = hv[4] | (hv[5] << 16); hq.w = hv[6] | (hv[7] << 16);
  lq.x = lv[0] | (lv[1] << 16); lq.y = lv[2] | (lv[3] << 16);
  lq.z = lv[4] | (lv[5] << 16); lq.w = lv[6] | (lv[7] << 16);

  const size_t base = ((size_t)(g * 4 + nt) * 2) * 1024 + (size_t)l * 16;
  *reinterpret_cast<uint4*>(wsb + base)        = hq;   // hi
  *reinterpret_cast<uint4*>(wsb + base + 1024) = lq;   // lo
}

union BF8 { bf16x8 v; ushort u[8]; };

__device__ __forceinline__ void cvt_hilo(const float4& a, const float4& b,
                                         bf16x8& hi, bf16x8& lo) {
  const float f[8] = {a.x, a.y, a.z, a.w, b.x, b.y, b.z, b.w};
  BF8 H, L;
#pragma unroll
  for (int i = 0; i < 8; ++i) {
    const unsigned u = __float_as_uint(f[i]);
    H.u[i] = (ushort)(u >> 16);                                 // exact prefix
    L.v[i] = (__bf16)(f[i] - __uint_as_float(u & 0xffff0000u)); // residual, RNE
  }
  hi = H.v; lo = L.v;
}

__device__ __forceinline__ bf16x8 bc(const uint4& q) {
  return __builtin_bit_cast(bf16x8, q);
}

// ---------------------------------------------------------------------------
// router_gemm v10: barrier-interval amortization. R6-R9 ledger: bytes -35%
// -> -4us, occupancy x1.7 -> 0, blocks/CU 2->4 -> 0, counted vmcnt -> -1us.
// Invariant cost = 32 sync intervals x ~2600 cyc with only ~6 wave-MFMA
// each (m233: the 2-phase skeleton is ~72% when MFMA/interval is small).
// BK=64: 8 chunks x 2 barriers = 16 intervals, 12 MFMA + 16 reads per wave
// each. Counted vmcnt (6 gl_lds/chunk, 2-deep, wait vmcnt(6); drain only on
// the last chunk). setprio(1) around MFMA cluster (T5, role-split pays).
// LDS 96 KB -> 1 block/CU (cross-block overlap measured worthless R6/R7).
// All bijections/swizzle/tail/epilogue verbatim from R8/R9 passes; swizzle
// extends to 16 slots (XOR low-3 bits only, same bank algebra, bijective).
// ---------------------------------------------------------------------------
__global__ __launch_bounds__(512, 2) void router_gemm(
    const float* __restrict__ x,
    const unsigned char* __restrict__ wsb,
    float* __restrict__ part)          // [NTOK][KSPLIT][128]
{
  __shared__ unsigned char lds[LDS_BYTES];

  const int tid  = threadIdx.x;
  const int wid  = tid >> 6;           // 0..7
  const int lane = tid & 63;
  const int mh   = wid >> 2;           // m-sub (32 tokens)
  const int nt   = wid & 3;            // 32-col tile
  const int tok0 = blockIdx.x * BM;
  const int ks   = blockIdx.y;
  const int kbase = ks * KQ;

  // ---- staging roles ----
  // x chunk = 64 rows x 256 B (16 slots of 16B). Thread t covers
  // (row = t>>4, slot = t&15) for rows 0..31 (write 0) and rows 32..63
  // (write 1, +8192). Source pre-swizzled: slot' = slot ^ (row & 7)
  // (low-3-bit XOR; rows 32.. have same row&7). LDS dest linear.
  const int xrow  = tid >> 4;          // 0..31
  const int xslot = tid & 15;
  const float* xsrc0 = x + (size_t)(tok0 + xrow) * DD + kbase
                         + ((xslot ^ (xrow & 7)) << 2);
  const float* xsrc1 = x + (size_t)(tok0 + 32 + xrow) * DD + kbase
                         + ((xslot ^ (xrow & 7)) << 2);
  // B: chunk c = 4 g-steps = 32 KB at bsrc + c*32768
  const unsigned char* bsrc = wsb + (size_t)(ks * (KQ / 16)) * 8192
                                  + (size_t)tid * 16;

  // ---- compute-role constants ----
  const int arow = lane & 31;
  const int atl  = lane >> 5;
  const int xswz = arow & 7;

  f32x16 acc = {0.f,0.f,0.f,0.f,0.f,0.f,0.f,0.f,
                0.f,0.f,0.f,0.f,0.f,0.f,0.f,0.f};

  // stage chunk cc into buffer b: 6 gl_lds per thread (2 x + 4 B)
  auto STAGE = [&](int cc, int b) {
    gl_lds16(xsrc0 + cc * BK, &lds[XBUF_OFF(b) + tid * 16]);
    gl_lds16(xsrc1 + cc * BK, &lds[XBUF_OFF(b) + 8192 + tid * 16]);
    const unsigned char* bs = bsrc + (size_t)cc * 32768;
#pragma unroll
    for (int j = 0; j < 4; ++j)
      gl_lds16(bs + j * 8192, &lds[BBUF_OFF(b) + j * 8192 + tid * 16]);
  };

  // ---- prologue: fill the 2-deep pipeline (12 outstanding, no drain) ----
  STAGE(0, 0);
  STAGE(1, 1);

#pragma unroll
  for (int c = 0; c < NCH; ++c) {
    // wait for chunk c's 6 loads only (oldest-first); keep c+1 in flight
    if (c < NCH - 1) asm volatile("s_waitcnt vmcnt(6)" ::: "memory");
    else             asm volatile("s_waitcnt vmcnt(0)" ::: "memory");
    __builtin_amdgcn_s_barrier();        // all waves' chunk-c data in LDS
    __builtin_amdgcn_sched_barrier(0);

    // ---- compute chunk c from buffer c&1 (LDS only): 4 ksteps, 12 MFMA ----
    const unsigned char* xb = &lds[XBUF_OFF(c & 1)];
    const unsigned char* bb = &lds[BBUF_OFF(c & 1)];
    __builtin_amdgcn_s_setprio(1);
#pragma unroll
    for (int s = 0; s < 4; ++s) {
      const int sl0 = (4 * s + 2 * atl) ^ xswz;        // XOR low-3 bits only
      const int sl1 = (4 * s + 2 * atl + 1) ^ xswz;
      const float4 xa = *reinterpret_cast<const float4*>(
          xb + (32 * mh + arow) * 256 + sl0 * 16);
      const float4 xv = *reinterpret_cast<const float4*>(
          xb + (32 * mh + arow) * 256 + sl1 * 16);
      const unsigned char* q = bb + s * 8192 + nt * 2048 + lane * 16;
      const uint4 bh = *reinterpret_cast<const uint4*>(q);
      const uint4 bl = *reinterpret_cast<const uint4*>(q + 1024);

      bf16x8 ahi, alo;
      cvt_hilo(xa, xv, ahi, alo);
      acc = __builtin_amdgcn_mfma_f32_32x32x16_bf16(ahi, bc(bh), acc, 0, 0, 0);
      acc = __builtin_amdgcn_mfma_f32_32x32x16_bf16(ahi, bc(bl), acc, 0, 0, 0);
      acc = __builtin_amdgcn_mfma_f32_32x32x16_bf16(alo, bc(bh), acc, 0, 0, 0);
    }
    __builtin_amdgcn_s_setprio(0);

    asm volatile("s_waitcnt lgkmcnt(0)" ::: "memory");  // my reads consumed
    __builtin_amdgcn_s_barrier();        // all waves done reading buf[c&1]
    __builtin_amdgcn_sched_barrier(0);

    if (c + 2 < NCH) STAGE(c + 2, c & 1);   // overwrite freed buffer
  }

  // ---- tail: acc -> LDS [64][128] f32 (overlays buffers), coalesced store ----
  // C/D map (validated R1-R9): col = lane&31, row = (q&3)+8*(q>>2)+4*(lane>>5)
  float* Lp = reinterpret_cast<float*>(lds);
  const int ccol = nt * 32 + (lane & 31);
#pragma unroll
  for (int q = 0; q < 16; ++q) {
    const int r = 32 * mh + (q & 3) + 8 * (q >> 2) + 4 * atl;
    Lp[r * 128 + ccol] = acc[q];
  }
  __syncthreads();
#pragma unroll
  for (int rr = 0; rr < 8; ++rr) {
    const int r = 8 * wid + rr;
    const float2 v = *reinterpret_cast<const float2*>(&Lp[r * 128 + 2 * lane]);
    *reinterpret_cast<float2*>(
        part + ((size_t)(tok0 + r) * KSPLIT + ks) * 128 + 2 * lane) = v;
  }
}

// ---------------------------------------------------------------------------
// Epilogue (R0/R4/R9-proven): one wave per token. Sum KSPLIT partials,
// softplus-noise, top-2 (desc value, asc index), softmax over 2, scatter.
// ---------------------------------------------------------------------------
__global__ __launch_bounds__(256) void router_epilogue(
    const float* __restrict__ part,      // [NTOK][KSPLIT][128]
    const float* __restrict__ noise_eps, // [NTOK][EE]
    float* __restrict__ out)
{
  const int t    = blockIdx.x * 4 + (threadIdx.x >> 6);
  const int lane = threadIdx.x & 63;

  const float* p = part + (size_t)t * KSPLIT * 128;
  float g = 0.0f, nraw = 0.0f;
#pragma unroll
  for (int s = 0; s < KSPLIT; ++s) {
    g    += p[s * 128 + lane];
    nraw += p[s * 128 + EE + lane];
  }
  const float ep = noise_eps[(size_t)t * EE + lane];

  const float sp = fmaxf(nraw, 0.0f) + log1pf(expf(-fabsf(nraw)));
  const float z  = fmaf(sp, ep, g);

  float v1 = z; int i1 = lane;
#pragma unroll
  for (int off = 32; off >= 1; off >>= 1) {
    const float ov = __shfl_xor(v1, off, 64);
    const int   oi = __shfl_xor(i1, off, 64);
    if (ov > v1 || (ov == v1 && oi < i1)) { v1 = ov; i1 = oi; }
  }
  float v2 = (lane == i1) ? -INFINITY : z; int i2 = lane;
#pragma unroll
  for (int off = 32; off >= 1; off >>= 1) {
    const float ov = __shfl_xor(v2, off, 64);
    const int   oi = __shfl_xor(i2, off, 64);
    if (ov > v2 || (ov == v2 && oi < i2)) { v2 = ov; i2 = oi; }
  }

  const float e2 = expf(v2 - v1);
  const float denom = 1.0f + e2;
  const float p1 = 1.0f / denom;
  const float p2 = e2 / denom;

  out[PROB_OFF + (size_t)t * EE + lane] =
      (lane == i1) ? p1 : ((lane == i2) ? p2 : 0.0f);

  if (lane == 0) {
    out[IDX_OFF + t * 2 + 0] = (float)i1;
    out[IDX_OFF + t * 2 + 1] = (float)i2;
  }

  out[MASK_OFF + 0 * MASK_K_STRIDE + (size_t)t * EE + lane] = (lane == i1) ? 1.0f : 0.0f;
  out[MASK_OFF + 1 * MASK_K_STRIDE + (size_t)t * EE + lane] = (lane == i2) ? 1.0f : 0.0f;
}

// ---------------------------------------------------------------------------
extern "C" void kernel_launch(void* const* d_in, const int* in_sizes, int n_in,
                              void* d_out, int out_size, void* d_ws, size_t ws_size,
                              hipStream_t stream) {
  const float* x   = (const float*)d_in[0];
  const float* eps = (const float*)d_in[1];
  const float* wg  = (const float*)d_in[2];
  const float* wn  = (const float*)d_in[3];

  unsigned char* wsb = (unsigned char*)d_ws;            // 1 MB weight frags
  float* part = (float*)(wsb + (1 << 20));              // 16 MB partials

  prep_w<<<dim3(128), dim3(256), 0, stream>>>(wg, wn, wsb);
  router_gemm<<<dim3(NTOK / BM, KSPLIT), dim3(512), 0, stream>>>(x, wsb, part);
  router_epilogue<<<dim3(NTOK / 4), dim3(256), 0, stream>>>(part, eps,
                                                            (float*)d_out);
}

// Round 11
// 122.719 us; speedup vs baseline: 1.0390x; 1.0390x over previous
//
#include <hip/hip_runtime.h>
#include <math.h>

// Problem constants
#define DD     2048
#define EE     64
#define NTOK   8192
#define BM     256              // tokens per block tile
#define KSPLIT 8                // k-split; ks = blockIdx.x & 7 -> XCD-pinned
#define KQ     256              // k per block
#define BK     32               // k per staged chunk
#define NCH    (KQ / BK)        // 8 chunks

// Output layout (all read back as float32 by harness)
#define PROB_OFF 0
#define IDX_OFF  524288
#define MASK_OFF 540672
#define MASK_K_STRIDE (NTOK * EE)

// LDS: 2-deep pipeline. xbuf 32 KB + bbuf 16 KB per stage = 96 KB total
#define XBUF_OFF(b) ((b) * 49152)
#define BBUF_OFF(b) ((b) * 49152 + 32768)
#define LDS_BYTES   98304

typedef __bf16 bf16x8 __attribute__((ext_vector_type(8)));
typedef float  f32x16 __attribute__((ext_vector_type(16)));

__device__ __forceinline__ unsigned f2bf_rne(float f) {
  unsigned u = __float_as_uint(f);
  return (u + 0x7fffu + ((u >> 16) & 1u)) >> 16;   // low 16 bits = bf16
}
__device__ __forceinline__ float bf2f(unsigned h) {
  return __uint_as_float(h << 16);
}

// async 16B global->LDS DMA (no VGPR round-trip; tracked by vmcnt)
__device__ __forceinline__ void gl_lds16(const void* g, void* l) {
  __builtin_amdgcn_global_load_lds(
      (const __attribute__((address_space(1))) unsigned int*)g,
      (__attribute__((address_space(3))) unsigned int*)l,
      16, 0, 0);
}

// ---------------------------------------------------------------------------
// prep_w: weights -> MFMA-fragment-ready bf16 hi/lo in workspace (1 MB).
// Fragment bijection (validated end-to-end by R1-R10 passes):
//   slot (g, nt, mat, lane, i)  <->  B[k][c],  k = 16*g + 8*(lane>>5) + i,
//   c = 32*nt + (lane&31),  (c<64 -> gate, else noise).
// Byte addr = ((g*4 + nt)*2 + mat)*1024 + lane*16 + 2*i.
// ---------------------------------------------------------------------------
__global__ __launch_bounds__(256) void prep_w(
    const float* __restrict__ wg, const float* __restrict__ wn,
    unsigned char* __restrict__ wsb)
{
  const int t  = blockIdx.x * 256 + threadIdx.x;   // 0..32767
  const int l  = t & 63;
  const int nt = (t >> 6) & 3;
  const int g  = t >> 8;                           // 0..127 (16-k steps)
  const int colg = nt * 32 + (l & 31);             // 0..127
  const int kb   = g * 16 + 8 * (l >> 5);
  const float* wsrc = (colg < EE) ? (wg + colg) : (wn + (colg - EE));

  unsigned hv[8], lv[8];
#pragma unroll
  for (int i = 0; i < 8; ++i) {
    const float v = wsrc[(size_t)(kb + i) * EE];
    const unsigned h = f2bf_rne(v);
    hv[i] = h;
    lv[i] = f2bf_rne(v - bf2f(h));
  }
  uint4 hq, lq;
  hq.x = hv[0] | (hv[1] << 16); hq.y = hv[2] | (hv[3] << 16);
  hq.z = hv[4] | (hv[5] << 16); hq.w = hv[6] | (hv[7] << 16);
  lq.x = lv[0] | (lv[1] << 16); lq.y = lv[2] | (lv[3] << 16);
  lq.z = lv[4] | (lv[5] << 16); lq.w = lv[6] | (lv[7] << 16);

  const size_t base = ((size_t)(g * 4 + nt) * 2) * 1024 + (size_t)l * 16;
  *reinterpret_cast<uint4*>(wsb + base)        = hq;   // hi
  *reinterpret_cast<uint4*>(wsb + base + 1024) = lq;   // lo
}

union BF8 { bf16x8 v; ushort u[8]; };

__device__ __forceinline__ void cvt_hilo(const float4& a, const float4& b,
                                         bf16x8& hi, bf16x8& lo) {
  const float f[8] = {a.x, a.y, a.z, a.w, b.x, b.y, b.z, b.w};
  BF8 H, L;
#pragma unroll
  for (int i = 0; i < 8; ++i) {
    const unsigned u = __float_as_uint(f[i]);
    H.u[i] = (ushort)(u >> 16);                                 // exact prefix
    L.v[i] = (__bf16)(f[i] - __uint_as_float(u & 0xffff0000u)); // residual, RNE
  }
  hi = H.v; lo = L.v;
}

__device__ __forceinline__ bf16x8 bc(const uint4& q) {
  return __builtin_bit_cast(bf16x8, q);
}

// ---------------------------------------------------------------------------
// router_gemm v11: register-blocked 64x64 wave tile. R10 post-mortem: LDS
// pipe is the largest busy term; old shape paid 1.33 ds_read_b128 per MFMA
// (1 acc tile/wave). Here each wave owns 2x2 32x32 accs: per kstep 4 A +
// 4 B reads feed 12 MFMAs (0.67 reads/MFMA) and x is converted once (no
// nt redundancy). Block 256tok x 128col, 8 waves (4 mh x 2 ntp), KSPLIT=8,
// grid 256 = 1 block/CU; ks = bid&7 pins each k-slice to one XCD (round-
// robin dispatch) -> 128 KB B-slice L2-resident, B chip traffic ~1 MB.
// R9-proven counted-vmcnt 2-deep pipeline (6 gl_lds/chunk, vmcnt(6), drain
// only last chunk); validated swizzle/bijections/C-D map verbatim.
// ---------------------------------------------------------------------------
__global__ __launch_bounds__(512, 2) void router_gemm(
    const float* __restrict__ x,
    const unsigned char* __restrict__ wsb,
    float* __restrict__ part)          // [NTOK][KSPLIT][128]
{
  __shared__ unsigned char lds[LDS_BYTES];

  const int tid  = threadIdx.x;
  const int wid  = tid >> 6;           // 0..7
  const int lane = tid & 63;
  const int mh   = wid >> 1;           // 0..3: 64-token group
  const int ntp  = wid & 1;            // 0..1: 64-col group
  const int bid  = blockIdx.x;
  const int ks   = bid & 7;            // XCD-pinned k-slice
  const int mg   = bid >> 3;           // 0..31
  const int tok0 = mg * BM;
  const int kbase = ks * KQ;

  // ---- staging roles ----
  // x chunk = 256 rows x 128 B (8 slots of 16B) = 2048 slots; thread t
  // covers u = j*512 + t, j=0..3: row = u>>3, sl = t&7. Source pre-swizzled
  // sl^(row&7) (validated law); LDS dest linear u*16.
  const int xsl = tid & 7;
  // B chunk = 16 KB: u = j*512 + t, j=0..1
  const unsigned char* bsrc = wsb + (size_t)ks * 131072 + (size_t)tid * 16;

  // ---- compute-role constants ----
  const int arow = lane & 31;
  const int atl  = lane >> 5;
  const int xswz = arow & 7;

  f32x16 a00 = {0.f,0.f,0.f,0.f,0.f,0.f,0.f,0.f,0.f,0.f,0.f,0.f,0.f,0.f,0.f,0.f};
  f32x16 a01 = a00, a10 = a00, a11 = a00;   // [row-group g][nt-tile t]

  // stage chunk cc into buffer b: 6 gl_lds per thread (4 x + 2 B)
  auto STAGE = [&](int cc, int b) {
#pragma unroll
    for (int j = 0; j < 4; ++j) {
      const int row = j * 64 + (tid >> 3);
      const float* src = x + (size_t)(tok0 + row) * DD + kbase + cc * BK
                           + ((xsl ^ (row & 7)) << 2);
      gl_lds16(src, &lds[XBUF_OFF(b) + j * 8192 + tid * 16]);
    }
    const unsigned char* bs = bsrc + (size_t)cc * 16384;
    gl_lds16(bs,        &lds[BBUF_OFF(b) + tid * 16]);
    gl_lds16(bs + 8192, &lds[BBUF_OFF(b) + 8192 + tid * 16]);
  };

  // ---- prologue: fill the 2-deep pipeline (12 outstanding, no drain) ----
  STAGE(0, 0);
  STAGE(1, 1);

#pragma unroll
  for (int c = 0; c < NCH; ++c) {
    if (c < NCH - 1) asm volatile("s_waitcnt vmcnt(6)" ::: "memory");
    else             asm volatile("s_waitcnt vmcnt(0)" ::: "memory");
    __builtin_amdgcn_s_barrier();        // all waves' chunk-c data in LDS
    __builtin_amdgcn_sched_barrier(0);

    // ---- compute chunk c from buffer c&1: 2 ksteps x 12 MFMA ----
    const unsigned char* xb = &lds[XBUF_OFF(c & 1)];
    const unsigned char* bb = &lds[BBUF_OFF(c & 1)];
    __builtin_amdgcn_s_setprio(1);
#pragma unroll
    for (int s = 0; s < 2; ++s) {
      // A: two 32-row groups, 2 b128 each, converted once
      bf16x8 ahi[2], alo[2];
#pragma unroll
      for (int g = 0; g < 2; ++g) {
        const int r = 64 * mh + 32 * g + arow;
        const int sl0 = (4 * s + 2 * atl) ^ xswz;
        const int sl1 = (4 * s + 2 * atl + 1) ^ xswz;
        const float4 xa = *reinterpret_cast<const float4*>(
            xb + r * 128 + sl0 * 16);
        const float4 xv = *reinterpret_cast<const float4*>(
            xb + r * 128 + sl1 * 16);
        cvt_hilo(xa, xv, ahi[g], alo[g]);
      }
      // B: two nt tiles (cols 64*ntp + 32*t), hi+lo each
#pragma unroll
      for (int t = 0; t < 2; ++t) {
        const int ntg = 2 * ntp + t;
        const unsigned char* q = bb + s * 8192 + ntg * 2048 + lane * 16;
        const uint4 bh = *reinterpret_cast<const uint4*>(q);
        const uint4 bl = *reinterpret_cast<const uint4*>(q + 1024);
        f32x16& r0 = t ? a01 : a00;
        f32x16& r1 = t ? a11 : a10;
        r0 = __builtin_amdgcn_mfma_f32_32x32x16_bf16(ahi[0], bc(bh), r0, 0, 0, 0);
        r0 = __builtin_amdgcn_mfma_f32_32x32x16_bf16(ahi[0], bc(bl), r0, 0, 0, 0);
        r0 = __builtin_amdgcn_mfma_f32_32x32x16_bf16(alo[0], bc(bh), r0, 0, 0, 0);
        r1 = __builtin_amdgcn_mfma_f32_32x32x16_bf16(ahi[1], bc(bh), r1, 0, 0, 0);
        r1 = __builtin_amdgcn_mfma_f32_32x32x16_bf16(ahi[1], bc(bl), r1, 0, 0, 0);
        r1 = __builtin_amdgcn_mfma_f32_32x32x16_bf16(alo[1], bc(bh), r1, 0, 0, 0);
      }
    }
    __builtin_amdgcn_s_setprio(0);

    asm volatile("s_waitcnt lgkmcnt(0)" ::: "memory");  // my reads consumed
    __builtin_amdgcn_s_barrier();        // all waves done reading buf[c&1]
    __builtin_amdgcn_sched_barrier(0);

    if (c + 2 < NCH) STAGE(c + 2, c & 1);   // overwrite freed buffer
  }

  // ---- tail: direct stores (2x128B segments per inst). C/D map validated
  // R1-R10: col = lane&31, row = (q&3)+8*(q>>2)+4*(lane>>5) ----
#pragma unroll
  for (int g = 0; g < 2; ++g) {
#pragma unroll
    for (int t = 0; t < 2; ++t) {
      const f32x16& a = g ? (t ? a11 : a10) : (t ? a01 : a00);
      const int colb = 64 * ntp + 32 * t + (lane & 31);
#pragma unroll
      for (int q = 0; q < 16; ++q) {
        const int tok = tok0 + 64 * mh + 32 * g
                      + (q & 3) + 8 * (q >> 2) + 4 * atl;
        part[((size_t)tok * KSPLIT + ks) * 128 + colb] = a[q];
      }
    }
  }
}

// ---------------------------------------------------------------------------
// Epilogue (R0/R4/R9-proven): one wave per token. Sum KSPLIT partials,
// softplus-noise, top-2 (desc value, asc index), softmax over 2, scatter.
// ---------------------------------------------------------------------------
__global__ __launch_bounds__(256) void router_epilogue(
    const float* __restrict__ part,      // [NTOK][KSPLIT][128]
    const float* __restrict__ noise_eps, // [NTOK][EE]
    float* __restrict__ out)
{
  const int t    = blockIdx.x * 4 + (threadIdx.x >> 6);
  const int lane = threadIdx.x & 63;

  const float* p = part + (size_t)t * KSPLIT * 128;
  float g = 0.0f, nraw = 0.0f;
#pragma unroll
  for (int s = 0; s < KSPLIT; ++s) {
    g    += p[s * 128 + lane];
    nraw += p[s * 128 + EE + lane];
  }
  const float ep = noise_eps[(size_t)t * EE + lane];

  const float sp = fmaxf(nraw, 0.0f) + log1pf(expf(-fabsf(nraw)));
  const float z  = fmaf(sp, ep, g);

  float v1 = z; int i1 = lane;
#pragma unroll
  for (int off = 32; off >= 1; off >>= 1) {
    const float ov = __shfl_xor(v1, off, 64);
    const int   oi = __shfl_xor(i1, off, 64);
    if (ov > v1 || (ov == v1 && oi < i1)) { v1 = ov; i1 = oi; }
  }
  float v2 = (lane == i1) ? -INFINITY : z; int i2 = lane;
#pragma unroll
  for (int off = 32; off >= 1; off >>= 1) {
    const float ov = __shfl_xor(v2, off, 64);
    const int   oi = __shfl_xor(i2, off, 64);
    if (ov > v2 || (ov == v2 && oi < i2)) { v2 = ov; i2 = oi; }
  }

  const float e2 = expf(v2 - v1);
  const float denom = 1.0f + e2;
  const float p1 = 1.0f / denom;
  const float p2 = e2 / denom;

  out[PROB_OFF + (size_t)t * EE + lane] =
      (lane == i1) ? p1 : ((lane == i2) ? p2 : 0.0f);

  if (lane == 0) {
    out[IDX_OFF + t * 2 + 0] = (float)i1;
    out[IDX_OFF + t * 2 + 1] = (float)i2;
  }

  out[MASK_OFF + 0 * MASK_K_STRIDE + (size_t)t * EE + lane] = (lane == i1) ? 1.0f : 0.0f;
  out[MASK_OFF + 1 * MASK_K_STRIDE + (size_t)t * EE + lane] = (lane == i2) ? 1.0f : 0.0f;
}

// ---------------------------------------------------------------------------
extern "C" void kernel_launch(void* const* d_in, const int* in_sizes, int n_in,
                              void* d_out, int out_size, void* d_ws, size_t ws_size,
                              hipStream_t stream) {
  const float* x   = (const float*)d_in[0];
  const float* eps = (const float*)d_in[1];
  const float* wg  = (const float*)d_in[2];
  const float* wn  = (const float*)d_in[3];

  unsigned char* wsb = (unsigned char*)d_ws;            // 1 MB weight frags
  float* part = (float*)(wsb + (1 << 20));              // 32 MB partials

  prep_w<<<dim3(128), dim3(256), 0, stream>>>(wg, wn, wsb);
  router_gemm<<<dim3((NTOK / BM) * KSPLIT), dim3(512), 0, stream>>>(x, wsb,
                                                                    part);
  router_epilogue<<<dim3(NTOK / 4), dim3(256), 0, stream>>>(part, eps,
                                                            (float*)d_out);
}